// Round 4
// baseline (47.269 us; speedup 1.0000x reference)
//
#include <hip/hip_runtime.h>
#include <hip/hip_bf16.h>

#define SEQL 4096
#define DIM  1024
#define SEGLEN 8
#define NSEG (SEQL / SEGLEN)   // 512 (worst case: every token a boundary)
#define WCAP 64                // max backward-window entries per segment
#define DSCUT -16.6f           // exp(-16.6) ~ 6e-8; tolerance is 8.9e-2

// ---------------------------------------------------------------------------
// Kernel 1: ALL channel-independent work. 1 block/batch, 1024 thr, 4 tok/thr.
//  - compaction (boundary pos, b=p) via paired (int,float) wave-shuffle scan
//  - log-prefix S = cumsum(log(1-p)) over boundaries (same scan, fused)
//  - per segment: window weights w_l = exp(S[k0-1]-S[j])*b[j] (prefix-monotone
//    cutoff), positions, in-segment coefs, meta {wlen, segn, snext}
// ---------------------------------------------------------------------------
__global__ __launch_bounds__(1024) void prep_kernel(
    const float* __restrict__ prob, const int* __restrict__ mask,
    int4*  __restrict__ seg_meta,    // [b][NSEG] {wlen, segn, snext, 0}
    float* __restrict__ win_w,       // [b][NSEG][WCAP]
    int*   __restrict__ win_p,       // [b][NSEG][WCAP]
    float* __restrict__ seg_a,       // [b][NSEG][SEGLEN]
    float* __restrict__ seg_b,       // [b][NSEG][SEGLEN]
    int*   __restrict__ seg_p) {     // [b][NSEG][SEGLEN]
  const int b = blockIdx.x;
  const int tid = threadIdx.x, wid = tid >> 6, lane = tid & 63;

  __shared__ int   pos_l[SEQL];
  __shared__ float b_l[SEQL];
  __shared__ float S_l[SEQL];
  __shared__ int   wsC[16];
  __shared__ float wsS[16];

  const int*   mb = mask + b * SEQL;
  const float* pb = prob + b * SEQL;
  int4   m4 = ((const int4*)mb)[tid];
  float4 p4 = ((const float4*)pb)[tid];
  int   mv[4] = { m4.x != 0, m4.y != 0, m4.z != 0, m4.w != 0 };
  float pv[4] = { p4.x, p4.y, p4.z, p4.w };
  float la[4];
  int cnt0 = 0; float ls0 = 0.f;
#pragma unroll
  for (int j = 0; j < 4; ++j) {
    float p = fminf(fmaxf(pv[j], 1e-4f), 1.f - 1e-4f);
    pv[j] = p;
    la[j] = mv[j] ? __logf(1.f - p) : 0.f;
    cnt0 += mv[j]; ls0 += la[j];
  }

  // paired wave-64 inclusive scan of (count, logsum)
  int ci = cnt0; float si = ls0;
#pragma unroll
  for (int off = 1; off < 64; off <<= 1) {
    int   tc = __shfl_up(ci, off, 64);
    float ts = __shfl_up(si, off, 64);
    if (lane >= off) { ci += tc; si += ts; }
  }
  if (lane == 63) { wsC[wid] = ci; wsS[wid] = si; }
  __syncthreads();
  if (tid < 16) {
    int c = wsC[tid]; float s = wsS[tid];
#pragma unroll
    for (int off = 1; off < 16; off <<= 1) {
      int   tc = __shfl_up(c, off, 64);
      float ts = __shfl_up(s, off, 64);
      if (tid >= off) { c += tc; s += ts; }
    }
    wsC[tid] = c; wsS[tid] = s;
  }
  __syncthreads();
  int   cntE = (wid ? wsC[wid - 1] : 0) + ci - cnt0;
  float curS = (wid ? wsS[wid - 1] : 0.f) + si - ls0;
  const int n = wsC[15];

  int run = cntE;
#pragma unroll
  for (int j = 0; j < 4; ++j) {
    curS += la[j];
    if (mv[j]) {
      pos_l[run] = tid * 4 + j;
      b_l[run]   = pv[j];
      S_l[run]   = curS;
      run++;
    }
  }
  __syncthreads();

  // per-segment metadata: wave `wid` handles segments wid, wid+16, ...
  for (int s = wid; s < NSEG; s += 16) {
    const int k0 = s * SEGLEN;
    const int segn = min(k0 + SEGLEN, n) - k0;
    const size_t so = (size_t)(b * NSEG + s);
    if (segn <= 0) {
      if (lane == 0) seg_meta[so] = make_int4(0, 0, 0, 0);
      continue;
    }
    const int j = k0 - 1 - lane;
    const bool valid = (j >= 0);
    const float base = (k0 > 0) ? S_l[k0 - 1] : 0.f;
    const float dS = valid ? (base - S_l[j]) : -1e9f;   // monotone in lane
    const bool keep = valid && (dS >= DSCUT);
    const unsigned long long bal = __ballot(keep);
    const int wlen = (int)__popcll(bal);                // keep is a prefix
    win_w[so * WCAP + lane] = keep ? __expf(dS) * b_l[j] : 0.f;
    win_p[so * WCAP + lane] = valid ? pos_l[j] : 0;
    if (lane < segn) {
      float bb = b_l[k0 + lane];
      seg_a[so * SEGLEN + lane] = 1.f - bb;
      seg_b[so * SEGLEN + lane] = bb;
      seg_p[so * SEGLEN + lane] = pos_l[k0 + lane];
    }
    if (lane == 0) {
      int snext = (k0 + segn < n) ? pos_l[k0 + segn] : SEQL;
      seg_meta[so] = make_int4(wlen, segn, snext, 0);
    }
  }
}

// ---------------------------------------------------------------------------
// Kernel 2: pure channel-parallel consumer. grid (NSEG, batch), 256 thr,
// thread = 4 channels (float4). Stage ~600B of segment data to LDS, then:
//   carry C = sum_l w_l * x[pos_l]   (independent float4 loads, 4-unrolled)
//   8-step EMA from C + fused run-length expansion (float4 stores).
// ---------------------------------------------------------------------------
__global__ __launch_bounds__(256) void consume_kernel(
    const float* __restrict__ h,
    const int4*  __restrict__ seg_meta,
    const float* __restrict__ win_w, const int* __restrict__ win_p,
    const float* __restrict__ seg_a, const float* __restrict__ seg_b,
    const int*   __restrict__ seg_p,
    float* __restrict__ out) {
  const int s = blockIdx.x, b = blockIdx.y;
  const size_t so = (size_t)(b * NSEG + s);
  const int4 meta = seg_meta[so];
  const int wlen = meta.x, segn = meta.y, snext = meta.z;
  if (segn <= 0) return;
  const int tid = threadIdx.x;
  const int d0 = tid * 4;

  __shared__ float lw[WCAP];
  __shared__ int   lp[WCAP];
  __shared__ float sa[SEGLEN], sb[SEGLEN];
  __shared__ int   sp[SEGLEN];
  if (tid < WCAP) {
    lw[tid] = win_w[so * WCAP + tid];
    lp[tid] = win_p[so * WCAP + tid];
  } else if (tid < WCAP + SEGLEN) {
    int k = tid - WCAP;
    if (k < segn) {
      sa[k] = seg_a[so * SEGLEN + k];
      sb[k] = seg_b[so * SEGLEN + k];
      sp[k] = seg_p[so * SEGLEN + k];
    }
  }
  __syncthreads();

  const float* hb = h + (size_t)b * SEQL * DIM;
  float* ob = out + (size_t)b * SEQL * DIM;

  float4 C = make_float4(0.f, 0.f, 0.f, 0.f);
  int l = 0;
  for (; l + 4 <= wlen; l += 4) {
    float w0 = lw[l], w1 = lw[l+1], w2 = lw[l+2], w3 = lw[l+3];
    const float4 x0 = *(const float4*)(hb + (size_t)lp[l]   * DIM + d0);
    const float4 x1 = *(const float4*)(hb + (size_t)lp[l+1] * DIM + d0);
    const float4 x2 = *(const float4*)(hb + (size_t)lp[l+2] * DIM + d0);
    const float4 x3 = *(const float4*)(hb + (size_t)lp[l+3] * DIM + d0);
    C.x = fmaf(w0, x0.x, fmaf(w1, x1.x, fmaf(w2, x2.x, fmaf(w3, x3.x, C.x))));
    C.y = fmaf(w0, x0.y, fmaf(w1, x1.y, fmaf(w2, x2.y, fmaf(w3, x3.y, C.y))));
    C.z = fmaf(w0, x0.z, fmaf(w1, x1.z, fmaf(w2, x2.z, fmaf(w3, x3.z, C.z))));
    C.w = fmaf(w0, x0.w, fmaf(w1, x1.w, fmaf(w2, x2.w, fmaf(w3, x3.w, C.w))));
  }
  for (; l < wlen; ++l) {
    float w0 = lw[l];
    const float4 x0 = *(const float4*)(hb + (size_t)lp[l] * DIM + d0);
    C.x = fmaf(w0, x0.x, C.x);
    C.y = fmaf(w0, x0.y, C.y);
    C.z = fmaf(w0, x0.z, C.z);
    C.w = fmaf(w0, x0.w, C.w);
  }

  float4 H = C;
  for (int kk = 0; kk < segn; ++kk) {
    float a = sa[kk], bc = sb[kk];
    int t = sp[kk];
    const float4 x = *(const float4*)(hb + (size_t)t * DIM + d0);
    H.x = fmaf(a, H.x, bc * x.x);
    H.y = fmaf(a, H.y, bc * x.y);
    H.z = fmaf(a, H.z, bc * x.z);
    H.w = fmaf(a, H.w, bc * x.w);
    int tn = (kk + 1 < segn) ? sp[kk + 1] : snext;
    for (int tt = t; tt < tn; ++tt) {
      *(float4*)(ob + (size_t)tt * DIM + d0) = H;
    }
  }
}

// ---------------------------------------------------------------------------
extern "C" void kernel_launch(void* const* d_in, const int* in_sizes, int n_in,
                              void* d_out, int out_size, void* d_ws, size_t ws_size,
                              hipStream_t stream) {
  const float* h    = (const float*)d_in[0];   // (2, 4096, 1024) f32
  const float* p    = (const float*)d_in[1];   // (2, 4096) f32
  const int*   mask = (const int*)d_in[2];     // (2, 4096) bool->int32
  float* out = (float*)d_out;                  // (2, 4096, 1024) f32

  // workspace layout
  char* w = (char*)d_ws;
  int4*  seg_meta = (int4*)w;                      w += 2 * NSEG * sizeof(int4);
  float* win_w    = (float*)w;                     w += 2 * NSEG * WCAP * sizeof(float);
  int*   win_p    = (int*)w;                       w += 2 * NSEG * WCAP * sizeof(int);
  float* seg_a    = (float*)w;                     w += 2 * NSEG * SEGLEN * sizeof(float);
  float* seg_b    = (float*)w;                     w += 2 * NSEG * SEGLEN * sizeof(float);
  int*   seg_p    = (int*)w;

  prep_kernel<<<dim3(2), 1024, 0, stream>>>(p, mask, seg_meta, win_w, win_p,
                                            seg_a, seg_b, seg_p);

  consume_kernel<<<dim3(NSEG, 2), 256, 0, stream>>>(h, seg_meta, win_w, win_p,
                                                    seg_a, seg_b, seg_p, out);
}

// Round 6
// 27.295 us; speedup vs baseline: 1.7318x; 1.7318x over previous
//
#include <hip/hip_runtime.h>
#include <hip/hip_bf16.h>

#define SEQL 4096
#define DIM  1024
#define SEGLEN 4
#define NSEG (SEQL / SEGLEN)   // 1024 segments/batch (worst case all boundaries)
#define WCAP 32                // max backward-window boundaries per segment
#define DSCUT -11.5f           // exp(-11.5)~1e-5; |state|~4 -> err 4e-5 << 8.9e-2

typedef float f32x4 __attribute__((ext_vector_type(4)));

// ---------------------------------------------------------------------------
// Kernel 1: ALL channel-independent work. 1 block/batch, 1024 thr, 4 tok/thr.
//  Phase 1: paired (count, log-prefix) wave-shuffle scan -> compaction:
//           pos_l, b_l (=p), S_l (= cumsum log(1-p) over boundaries).
//  Phase 2: per segment (2 segs per wave-iter, 32 lanes each, no shuffles):
//           window weights w_l = exp(S[k0-1]-S[j]) * b[j] with prefix-monotone
//           cutoff, positions, meta {wlen, segn, snext}.
// ---------------------------------------------------------------------------
__global__ __launch_bounds__(1024) void prep_kernel(
    const float* __restrict__ prob, const int* __restrict__ mask,
    int*   __restrict__ bpos,        // [b][SEQL] compacted boundary positions
    float* __restrict__ coefA,       // [b][SEQL] 1-p compacted
    float* __restrict__ coefB,       // [b][SEQL] p compacted
    int4*  __restrict__ seg_meta,    // [b][NSEG] {wlen, segn, snext, 0}
    float* __restrict__ win_w,       // [b][NSEG][WCAP]
    int*   __restrict__ win_p) {     // [b][NSEG][WCAP]
  const int b = blockIdx.x;
  const int tid = threadIdx.x, wid = tid >> 6, lane = tid & 63;

  __shared__ int   pos_l[SEQL];
  __shared__ float b_l[SEQL];
  __shared__ float S_l[SEQL];
  __shared__ int   wsC[16];
  __shared__ float wsS[16];

  int4   m4 = ((const int4*)(mask + b * SEQL))[tid];
  float4 p4 = ((const float4*)(prob + b * SEQL))[tid];
  int   mv[4] = { m4.x != 0, m4.y != 0, m4.z != 0, m4.w != 0 };
  float pv[4] = { p4.x, p4.y, p4.z, p4.w };
  float la[4];
  int cnt0 = 0; float ls0 = 0.f;
#pragma unroll
  for (int j = 0; j < 4; ++j) {
    float p = fminf(fmaxf(pv[j], 1e-4f), 1.f - 1e-4f);
    pv[j] = p;
    la[j] = mv[j] ? __logf(1.f - p) : 0.f;
    cnt0 += mv[j]; ls0 += la[j];
  }

  // paired wave-64 inclusive scan of (count, logsum)
  int ci = cnt0; float si = ls0;
#pragma unroll
  for (int off = 1; off < 64; off <<= 1) {
    int   tc = __shfl_up(ci, off, 64);
    float ts = __shfl_up(si, off, 64);
    if (lane >= off) { ci += tc; si += ts; }
  }
  if (lane == 63) { wsC[wid] = ci; wsS[wid] = si; }
  __syncthreads();
  if (tid < 16) {
    int c = wsC[tid]; float s = wsS[tid];
#pragma unroll
    for (int off = 1; off < 16; off <<= 1) {
      int   tc = __shfl_up(c, off, 64);
      float ts = __shfl_up(s, off, 64);
      if (tid >= off) { c += tc; s += ts; }
    }
    wsC[tid] = c; wsS[tid] = s;
  }
  __syncthreads();
  int   run  = (wid ? wsC[wid - 1] : 0) + ci - cnt0;
  float curS = (wid ? wsS[wid - 1] : 0.f) + si - ls0;
  const int n = wsC[15];

#pragma unroll
  for (int j = 0; j < 4; ++j) {
    curS += la[j];
    if (mv[j]) {
      pos_l[run] = tid * 4 + j;
      b_l[run]   = pv[j];
      S_l[run]   = curS;
      run++;
    }
  }
  __syncthreads();

  // coalesced write-out of compacted arrays
  for (int i = tid; i < n; i += 1024) {
    bpos[b * SEQL + i]  = pos_l[i];
    coefB[b * SEQL + i] = b_l[i];
    coefA[b * SEQL + i] = 1.f - b_l[i];
  }

  // Phase 2: two segments per wave-iteration (32 lanes each)
  const int g = lane >> 5, l = lane & 31;
  for (int s0 = wid * 2 + g; s0 < NSEG; s0 += 32) {
    const int s = s0;
    const int k0 = s * SEGLEN;
    const int segn = min(k0 + SEGLEN, n) - k0;   // may be <= 0
    const size_t so = (size_t)(b * NSEG + s);
    const int j = k0 - 1 - l;
    const bool act = (segn > 0);
    const bool valid = act && (j >= 0);
    const float base = (act && k0 > 0) ? S_l[k0 - 1] : 0.f;
    const float dS = valid ? (base - S_l[j]) : -1e9f;  // monotone in l
    const bool keep = dS >= DSCUT;
    const unsigned long long bal = __ballot(keep);
    const int wlen = (int)__popcll((bal >> (g * 32)) & 0xFFFFFFFFull);
    if (act) {
      win_w[so * WCAP + l] = keep ? __expf(dS) * b_l[j] : 0.f;
      win_p[so * WCAP + l] = keep ? pos_l[j] : 0;
    }
    if (l == 0) {
      int snext = (act && k0 + segn < n) ? pos_l[k0 + segn] : SEQL;
      seg_meta[so] = make_int4(act ? wlen : 0, act ? segn : 0, snext, 0);
    }
  }
}

// ---------------------------------------------------------------------------
// Kernel 2: pure channel-parallel consumer. grid (NSEG, batch), 256 thr,
// thread = 4 channels (float4). ~512 active blocks (2048 waves, 8/CU).
//   carry C = sum_l w_l * x[pos_l]  (4 independent accumulators, 4-ILP loads)
//   prefetch 4 in-segment rows, 4-step EMA, fused run-length expansion
//   with nontemporal float4 stores.
// ---------------------------------------------------------------------------
__global__ __launch_bounds__(256) void consume_kernel(
    const float* __restrict__ h, const int* __restrict__ bpos,
    const float* __restrict__ coefA, const float* __restrict__ coefB,
    const int4* __restrict__ seg_meta,
    const float* __restrict__ win_w, const int* __restrict__ win_p,
    float* __restrict__ out) {
  const int s = blockIdx.x, b = blockIdx.y;
  const size_t so = (size_t)(b * NSEG + s);
  const int4 meta = seg_meta[so];
  const int wlen = meta.x, segn = meta.y, snext = meta.z;
  if (segn <= 0) return;
  const int tid = threadIdx.x;
  const int k0 = s * SEGLEN;

  __shared__ float lw[WCAP];
  __shared__ int   lp[WCAP];
  __shared__ float sa[SEGLEN], sb[SEGLEN];
  __shared__ int   sp[SEGLEN];
  if (tid < WCAP) {
    lw[tid] = win_w[so * WCAP + tid];
    lp[tid] = win_p[so * WCAP + tid];
  } else if (tid < WCAP + SEGLEN) {
    int k = tid - WCAP;
    if (k < segn) {
      sa[k] = coefA[b * SEQL + k0 + k];
      sb[k] = coefB[b * SEQL + k0 + k];
      sp[k] = bpos[b * SEQL + k0 + k];
    }
  }
  __syncthreads();

  const float* hb = h + (size_t)b * SEQL * DIM;
  float* ob = out + (size_t)b * SEQL * DIM;
  const int d0 = tid * 4;

  float4 C0 = {0,0,0,0}, C1 = {0,0,0,0}, C2 = {0,0,0,0}, C3 = {0,0,0,0};
  int l = 0;
  for (; l + 4 <= wlen; l += 4) {
    float w0 = lw[l], w1 = lw[l+1], w2 = lw[l+2], w3 = lw[l+3];
    const float4 x0 = *(const float4*)(hb + (size_t)lp[l]   * DIM + d0);
    const float4 x1 = *(const float4*)(hb + (size_t)lp[l+1] * DIM + d0);
    const float4 x2 = *(const float4*)(hb + (size_t)lp[l+2] * DIM + d0);
    const float4 x3 = *(const float4*)(hb + (size_t)lp[l+3] * DIM + d0);
    C0.x = fmaf(w0, x0.x, C0.x); C0.y = fmaf(w0, x0.y, C0.y);
    C0.z = fmaf(w0, x0.z, C0.z); C0.w = fmaf(w0, x0.w, C0.w);
    C1.x = fmaf(w1, x1.x, C1.x); C1.y = fmaf(w1, x1.y, C1.y);
    C1.z = fmaf(w1, x1.z, C1.z); C1.w = fmaf(w1, x1.w, C1.w);
    C2.x = fmaf(w2, x2.x, C2.x); C2.y = fmaf(w2, x2.y, C2.y);
    C2.z = fmaf(w2, x2.z, C2.z); C2.w = fmaf(w2, x2.w, C2.w);
    C3.x = fmaf(w3, x3.x, C3.x); C3.y = fmaf(w3, x3.y, C3.y);
    C3.z = fmaf(w3, x3.z, C3.z); C3.w = fmaf(w3, x3.w, C3.w);
  }
  for (; l < wlen; ++l) {
    float w0 = lw[l];
    const float4 x0 = *(const float4*)(hb + (size_t)lp[l] * DIM + d0);
    C0.x = fmaf(w0, x0.x, C0.x); C0.y = fmaf(w0, x0.y, C0.y);
    C0.z = fmaf(w0, x0.z, C0.z); C0.w = fmaf(w0, x0.w, C0.w);
  }
  f32x4 H;
  H.x = (C0.x + C1.x) + (C2.x + C3.x);
  H.y = (C0.y + C1.y) + (C2.y + C3.y);
  H.z = (C0.z + C1.z) + (C2.z + C3.z);
  H.w = (C0.w + C1.w) + (C2.w + C3.w);

  // prefetch all in-segment rows (independent loads)
  float4 X[SEGLEN];
#pragma unroll
  for (int k = 0; k < SEGLEN; ++k) {
    int kk = (k < segn) ? k : 0;
    X[k] = *(const float4*)(hb + (size_t)sp[kk] * DIM + d0);
  }

#pragma unroll
  for (int k = 0; k < SEGLEN; ++k) {
    if (k >= segn) break;
    float a = sa[k], bc = sb[k];
    H.x = fmaf(a, H.x, bc * X[k].x);
    H.y = fmaf(a, H.y, bc * X[k].y);
    H.z = fmaf(a, H.z, bc * X[k].z);
    H.w = fmaf(a, H.w, bc * X[k].w);
    int t = sp[k];
    int tn = (k + 1 < segn) ? sp[k + 1] : snext;
    for (int tt = t; tt < tn; ++tt) {
      __builtin_nontemporal_store(H, (f32x4*)(ob + (size_t)tt * DIM + d0));
    }
  }
}

// ---------------------------------------------------------------------------
extern "C" void kernel_launch(void* const* d_in, const int* in_sizes, int n_in,
                              void* d_out, int out_size, void* d_ws, size_t ws_size,
                              hipStream_t stream) {
  const float* h    = (const float*)d_in[0];   // (2, 4096, 1024) f32
  const float* p    = (const float*)d_in[1];   // (2, 4096) f32
  const int*   mask = (const int*)d_in[2];     // (2, 4096) bool->int32
  float* out = (float*)d_out;                  // (2, 4096, 1024) f32

  // workspace layout (16B-aligned first)
  char* w = (char*)d_ws;
  int4*  seg_meta = (int4*)w;                  w += (size_t)2 * NSEG * sizeof(int4);
  float* win_w    = (float*)w;                 w += (size_t)2 * NSEG * WCAP * sizeof(float);
  int*   win_p    = (int*)w;                   w += (size_t)2 * NSEG * WCAP * sizeof(int);
  int*   bpos     = (int*)w;                   w += (size_t)2 * SEQL * sizeof(int);
  float* coefA    = (float*)w;                 w += (size_t)2 * SEQL * sizeof(float);
  float* coefB    = (float*)w;

  prep_kernel<<<dim3(2), 1024, 0, stream>>>(p, mask, bpos, coefA, coefB,
                                            seg_meta, win_w, win_p);

  consume_kernel<<<dim3(NSEG, 2), 256, 0, stream>>>(h, bpos, coefA, coefB,
                                                    seg_meta, win_w, win_p, out);
}

// Round 7
// 21.998 us; speedup vs baseline: 2.1488x; 1.2408x over previous
//
#include <hip/hip_runtime.h>
#include <hip/hip_bf16.h>

#define SEQL 4096
#define DIM  1024
#define SEGLEN 4
#define NSEG (SEQL / SEGLEN)   // 1024 segments/batch (worst case all boundaries)
#define WCAP 32                // max backward-window boundaries per segment
#define DSCUT -11.5f           // exp(-11.5)~1e-5; err ~4e-5 << 8.9e-2 tolerance

typedef float f32x4 __attribute__((ext_vector_type(4)));

// ---------------------------------------------------------------------------
// Kernel 1: compaction + log-prefix only (no per-segment windows any more).
// 1 block/batch, 1024 thr, 4 tok/thr.
//  - paired (count, logsum) wave-shuffle scan -> compacted pos, b=p,
//    S = cumsum(log(1-p)) over boundaries
//  - seg_meta {segn, snext}: one thread per segment, single pass.
// ---------------------------------------------------------------------------
__global__ __launch_bounds__(1024) void prep_kernel(
    const float* __restrict__ prob, const int* __restrict__ mask,
    int*   __restrict__ bpos,        // [b][SEQL] compacted boundary positions
    float* __restrict__ coefB,       // [b][SEQL] p compacted
    float* __restrict__ Sg,          // [b][SEQL] log-prefix over boundaries
    int2*  __restrict__ seg_meta) {  // [b][NSEG] {segn, snext}
  const int b = blockIdx.x;
  const int tid = threadIdx.x, wid = tid >> 6, lane = tid & 63;

  __shared__ int   pos_l[SEQL];
  __shared__ float b_l[SEQL];
  __shared__ float S_l[SEQL];
  __shared__ int   wsC[16];
  __shared__ float wsS[16];

  int4   m4 = ((const int4*)(mask + b * SEQL))[tid];
  float4 p4 = ((const float4*)(prob + b * SEQL))[tid];
  int   mv[4] = { m4.x != 0, m4.y != 0, m4.z != 0, m4.w != 0 };
  float pv[4] = { p4.x, p4.y, p4.z, p4.w };
  float la[4];
  int cnt0 = 0; float ls0 = 0.f;
#pragma unroll
  for (int j = 0; j < 4; ++j) {
    float p = fminf(fmaxf(pv[j], 1e-4f), 1.f - 1e-4f);
    pv[j] = p;
    la[j] = mv[j] ? __logf(1.f - p) : 0.f;
    cnt0 += mv[j]; ls0 += la[j];
  }

  // paired wave-64 inclusive scan of (count, logsum)
  int ci = cnt0; float si = ls0;
#pragma unroll
  for (int off = 1; off < 64; off <<= 1) {
    int   tc = __shfl_up(ci, off, 64);
    float ts = __shfl_up(si, off, 64);
    if (lane >= off) { ci += tc; si += ts; }
  }
  if (lane == 63) { wsC[wid] = ci; wsS[wid] = si; }
  __syncthreads();
  if (tid < 16) {
    int c = wsC[tid]; float s = wsS[tid];
#pragma unroll
    for (int off = 1; off < 16; off <<= 1) {
      int   tc = __shfl_up(c, off, 64);
      float ts = __shfl_up(s, off, 64);
      if (tid >= off) { c += tc; s += ts; }
    }
    wsC[tid] = c; wsS[tid] = s;
  }
  __syncthreads();
  int   run  = (wid ? wsC[wid - 1] : 0) + ci - cnt0;
  float curS = (wid ? wsS[wid - 1] : 0.f) + si - ls0;
  const int n = wsC[15];

#pragma unroll
  for (int j = 0; j < 4; ++j) {
    curS += la[j];
    if (mv[j]) {
      pos_l[run] = tid * 4 + j;
      b_l[run]   = pv[j];
      S_l[run]   = curS;
      run++;
    }
  }
  __syncthreads();

  // coalesced write-out of compacted arrays
  for (int i = tid; i < n; i += 1024) {
    bpos[b * SEQL + i]  = pos_l[i];
    coefB[b * SEQL + i] = b_l[i];
    Sg[b * SEQL + i]    = S_l[i];
  }

  // per-segment meta: exactly one thread per segment (NSEG == blockDim)
  {
    const int s = tid;
    const int k0 = s * SEGLEN;
    int segn = min(k0 + SEGLEN, n) - k0;
    if (segn < 0) segn = 0;
    int snext = (segn > 0 && k0 + segn < n) ? pos_l[k0 + segn] : SEQL;
    seg_meta[b * NSEG + s] = make_int2(segn, snext);
  }
}

// ---------------------------------------------------------------------------
// Kernel 2: consumer, channel-split x2. grid (NSEG, 2, batch), 128 thr,
// thread = 4 channels -> block covers channels [blockIdx.y*512, +512).
// ~1024 active blocks (4/CU). Window weights computed INLINE (32 independent
// exps from the precomputed log-prefix S; keep-set is a prefix by
// monotonicity). Then:
//   carry C = sum_l w_l * x[pos_l]  (4 independent accumulators, ILP loads)
//   prefetch 4 in-segment rows, 4-step EMA, fused run-length expansion
//   with nontemporal stores.
// ---------------------------------------------------------------------------
__global__ __launch_bounds__(128) void consume_kernel(
    const float* __restrict__ h, const int* __restrict__ bpos,
    const float* __restrict__ coefB, const float* __restrict__ Sg,
    const int2* __restrict__ seg_meta,
    float* __restrict__ out) {
  const int s = blockIdx.x, b = blockIdx.z;
  const int2 meta = seg_meta[(size_t)b * NSEG + s];
  const int segn = meta.x, snext = meta.y;
  if (segn <= 0) return;
  const int tid = threadIdx.x;
  const int k0 = s * SEGLEN;

  __shared__ float lw[WCAP];
  __shared__ int   lp[WCAP];
  __shared__ float sb[SEGLEN];
  __shared__ int   sp[SEGLEN];
  __shared__ int   wlen_s;

  if (tid < 64) {
    // wave 0, lanes 0..31: build window inline (independent exps)
    bool keep = false; float w = 0.f; int pos = 0;
    if (tid < 32) {
      int j = k0 - 1 - tid;
      if (j >= 0) {
        float dS = Sg[b * SEQL + k0 - 1] - Sg[b * SEQL + j];
        keep = (dS >= DSCUT);
        w = __expf(dS) * coefB[b * SEQL + j];
        pos = bpos[b * SEQL + j];
      }
    }
    unsigned long long bal = __ballot(keep);
    if (tid < 32) { lw[tid] = keep ? w : 0.f; lp[tid] = keep ? pos : 0; }
    if (tid == 0) wlen_s = (int)__popcll(bal);   // keep is a prefix
  } else {
    int k = tid - 64;
    if (k < segn) {
      sb[k] = coefB[b * SEQL + k0 + k];
      sp[k] = bpos[b * SEQL + k0 + k];
    }
  }
  __syncthreads();

  const float* hb = h + (size_t)b * SEQL * DIM;
  float* ob = out + (size_t)b * SEQL * DIM;
  const int d0 = (blockIdx.y * 128 + tid) * 4;
  const int wlen = wlen_s;

  float4 C0 = {0,0,0,0}, C1 = {0,0,0,0}, C2 = {0,0,0,0}, C3 = {0,0,0,0};
  int l = 0;
  for (; l + 4 <= wlen; l += 4) {
    float w0 = lw[l], w1 = lw[l+1], w2 = lw[l+2], w3 = lw[l+3];
    const float4 x0 = *(const float4*)(hb + (size_t)lp[l]   * DIM + d0);
    const float4 x1 = *(const float4*)(hb + (size_t)lp[l+1] * DIM + d0);
    const float4 x2 = *(const float4*)(hb + (size_t)lp[l+2] * DIM + d0);
    const float4 x3 = *(const float4*)(hb + (size_t)lp[l+3] * DIM + d0);
    C0.x = fmaf(w0, x0.x, C0.x); C0.y = fmaf(w0, x0.y, C0.y);
    C0.z = fmaf(w0, x0.z, C0.z); C0.w = fmaf(w0, x0.w, C0.w);
    C1.x = fmaf(w1, x1.x, C1.x); C1.y = fmaf(w1, x1.y, C1.y);
    C1.z = fmaf(w1, x1.z, C1.z); C1.w = fmaf(w1, x1.w, C1.w);
    C2.x = fmaf(w2, x2.x, C2.x); C2.y = fmaf(w2, x2.y, C2.y);
    C2.z = fmaf(w2, x2.z, C2.z); C2.w = fmaf(w2, x2.w, C2.w);
    C3.x = fmaf(w3, x3.x, C3.x); C3.y = fmaf(w3, x3.y, C3.y);
    C3.z = fmaf(w3, x3.z, C3.z); C3.w = fmaf(w3, x3.w, C3.w);
  }
  for (; l < wlen; ++l) {
    float w0 = lw[l];
    const float4 x0 = *(const float4*)(hb + (size_t)lp[l] * DIM + d0);
    C0.x = fmaf(w0, x0.x, C0.x); C0.y = fmaf(w0, x0.y, C0.y);
    C0.z = fmaf(w0, x0.z, C0.z); C0.w = fmaf(w0, x0.w, C0.w);
  }
  f32x4 H;
  H.x = (C0.x + C1.x) + (C2.x + C3.x);
  H.y = (C0.y + C1.y) + (C2.y + C3.y);
  H.z = (C0.z + C1.z) + (C2.z + C3.z);
  H.w = (C0.w + C1.w) + (C2.w + C3.w);

  // prefetch all in-segment rows (independent loads)
  float4 X[SEGLEN];
#pragma unroll
  for (int k = 0; k < SEGLEN; ++k) {
    int kk = (k < segn) ? k : 0;
    X[k] = *(const float4*)(hb + (size_t)sp[kk] * DIM + d0);
  }

#pragma unroll
  for (int k = 0; k < SEGLEN; ++k) {
    if (k >= segn) break;
    float bc = sb[k];
    float a = 1.f - bc;
    H.x = fmaf(a, H.x, bc * X[k].x);
    H.y = fmaf(a, H.y, bc * X[k].y);
    H.z = fmaf(a, H.z, bc * X[k].z);
    H.w = fmaf(a, H.w, bc * X[k].w);
    int t = sp[k];
    int tn = (k + 1 < segn) ? sp[k + 1] : snext;
    for (int tt = t; tt < tn; ++tt) {
      __builtin_nontemporal_store(H, (f32x4*)(ob + (size_t)tt * DIM + d0));
    }
  }
}

// ---------------------------------------------------------------------------
extern "C" void kernel_launch(void* const* d_in, const int* in_sizes, int n_in,
                              void* d_out, int out_size, void* d_ws, size_t ws_size,
                              hipStream_t stream) {
  const float* h    = (const float*)d_in[0];   // (2, 4096, 1024) f32
  const float* p    = (const float*)d_in[1];   // (2, 4096) f32
  const int*   mask = (const int*)d_in[2];     // (2, 4096) bool->int32
  float* out = (float*)d_out;                  // (2, 4096, 1024) f32

  // workspace layout
  char* w = (char*)d_ws;
  int2*  seg_meta = (int2*)w;                  w += (size_t)2 * NSEG * sizeof(int2);
  int*   bpos     = (int*)w;                   w += (size_t)2 * SEQL * sizeof(int);
  float* coefB    = (float*)w;                 w += (size_t)2 * SEQL * sizeof(float);
  float* Sg       = (float*)w;

  prep_kernel<<<dim3(2), 1024, 0, stream>>>(p, mask, bpos, coefB, Sg, seg_meta);

  consume_kernel<<<dim3(NSEG, 2, 2), 128, 0, stream>>>(h, bpos, coefB, Sg,
                                                       seg_meta, out);
}